// Round 11
// baseline (117.314 us; speedup 1.0000x reference)
//
#include <hip/hip_runtime.h>
#include <cstdint>
#include <cstddef>

#define THETA 1.2f
#define XI 0.3f
#define BDIM 8192
#define DDIM 512
#define NROWP 32           // 32 row-panels of 256 rows
#define NCOLP 64           // 64 col-panels of 128 cols
#define NUNITS 1056        // sum_{ti<32}(64-2*ti): 256x128 upper-tri units
#define GRID 512           // 2 blocks/CU resident; 2.06 units/block grid-stride
// upper-triangle-with-diagonal pair count: B*(B+1)/2
#define NPAIRS_UP (((double)BDIM * (double)(BDIM + 1)) * 0.5)

typedef float f32x4 __attribute__((ext_vector_type(4)));
typedef int i32x8 __attribute__((ext_vector_type(8)));

// ---------------------------------------------------------------------------
// Fragment-major ("tiled") fp8 layout (verified r6-r10):
//   frag F = (row/16)*4 + (kbyte/128)   -- 16 rows x 128 B of K = one MFMA frag
//   blob of 2048 B at F*2048; lane l holds its 32 B at offset l*32 -- exactly
//   the mfma_scale 16x16x128 operand order. Frag load = contiguous 2 KB/wave.
// ---------------------------------------------------------------------------

// Kernel 1: per-row L2 normalize fp32 -> fp8 e4m3 into tiled layout;
// sq[row]=||n||^2; zero counter.
__global__ __launch_bounds__(256) void normalize_rows(
    const float* __restrict__ x, unsigned char* __restrict__ nf8,
    float* __restrict__ sq, unsigned int* __restrict__ counter)
{
    if (blockIdx.x == 0 && threadIdx.x == 0) { *counter = 0u; }
    int row = blockIdx.x * 4 + (threadIdx.x >> 6);
    int l = threadIdx.x & 63;
    const float4* xr = (const float4*)(x + (size_t)row * DDIM);
    float4 f0 = xr[l];
    float4 f1 = xr[l + 64];
    float s = f0.x*f0.x + f0.y*f0.y + f0.z*f0.z + f0.w*f0.w
            + f1.x*f1.x + f1.y*f1.y + f1.z*f1.z + f1.w*f1.w;
    #pragma unroll
    for (int m = 1; m < 64; m <<= 1) s += __shfl_xor(s, m);
    float rn = rsqrtf(s);
    int pk0 = __builtin_amdgcn_cvt_pk_fp8_f32(f0.x * rn, f0.y * rn, 0, false);
    pk0     = __builtin_amdgcn_cvt_pk_fp8_f32(f0.z * rn, f0.w * rn, pk0, true);
    int pk1 = __builtin_amdgcn_cvt_pk_fp8_f32(f1.x * rn, f1.y * rn, 0, false);
    pk1     = __builtin_amdgcn_cvt_pk_fp8_f32(f1.z * rn, f1.w * rn, pk1, true);
    // tiled scatter: pk0 covers k=[4l,4l+4), pk1 covers k=[4l+256,4l+260)
    size_t base = (size_t)(row >> 4) * 4 * 2048;
    int within = ((row & 15) + ((l >> 3) & 3) * 16) * 32 + (l & 7) * 4;
    int kc0 = l >> 5;          // k=4l       -> kc in {0,1}
    int kc1 = (l >> 5) + 2;    // k=4l+256   -> kc in {2,3}
    *(int*)(nf8 + base + (size_t)kc0 * 2048 + within) = pk0;
    *(int*)(nf8 + base + (size_t)kc1 * 2048 + within) = pk1;
    if (l == 0) sq[row] = s * rn * rn;
}

// unit u -> (ti, tj): ti row-panel (256 rows), tj col-panel (128 cols),
// tj in [2*ti, 64). cum(t) = t*(65-t) units before row-panel t.
__device__ __forceinline__ void decode_unit(int u, int& ti, int& tj) {
    int t = (int)((65.0f - sqrtf(65.0f * 65.0f - 4.0f * (float)u)) * 0.5f);
    if (t > 31) t = 31;
    while (t < 31 && (t + 1) * (65 - (t + 1)) <= u) ++t;
    while (t > 0 && t * (65 - t) > u) --t;
    ti = t;
    tj = 2 * t + (u - t * (65 - t));
}

// Kernel 2: 256x128 units, 8 waves (2x4): per-wave 128 rows x 32 cols.
// r8's proven pipeline skeleton (counted vmcnt, two barriers/chunk, cross-
// tile carry), re-tiled so each barrier-pair covers 2x the MFMA work:
//  * A: 256 rows staged in LDS (32 KB/chunk, dbuf 64 KB), 4 x 1 KB DMA/wave.
//  * B: 128 cols direct-global frag-major, register-dbuf'd one chunk ahead
//    (2 frags = 16 regs per buffer).
//  * Per chunk per CU: 2 blk x 8 waves x 16 MFMA = 2214 cyc/SIMD of MFMA --
//    2x r5/r8/r10, which all plateaued at ~1100 cyc MFMA vs ~2200 cyc fixed
//    chunk cost (r10 falsified the latency theory: occupancy 2x'd, time
//    unchanged -> the cost is per-chunk machinery, so amortize it).
//  * Regs: acc 64 + bf-dbuf 32 + af 8 + addr ~40 ~= 150 << 256 cap (512,2).
//  * vmcnt(8): per chunk a wave issues 4 bf-loads + 4 DMA = 8 newer ops.
__global__ __launch_bounds__(512, 2) void gram_hinge(
    const unsigned char* __restrict__ nf8, const float* __restrict__ sq,
    const int* __restrict__ y, double* __restrict__ part,
    unsigned int* __restrict__ counter, float* __restrict__ out)
{
    __shared__ unsigned char As[2][32768];   // 64 KB: A chunk frags, dbuf
    __shared__ float wpart[8];
    __shared__ double dpart[8];
    __shared__ int is_last;

    int tid = threadIdx.x;
    int w = tid >> 6, l = tid & 63;
    int wr = w >> 2, wc = w & 3;      // 2x4 wave grid: 128-row x 32-col quadrant
    int lr = l & 15, q = l >> 4;

    // stage one chunk of A (16 frags = 32 KB): 4 x 1 KB DMA per wave (8 waves).
    auto stageA = [&](unsigned char* dAb, int pti, int pc) {
        #pragma unroll
        for (int i = 0; i < 4; ++i) {
            int t = w * 4 + i;               // 0..31
            int rf = t >> 1, half = t & 1;   // frag 0..15, half 0..1
            const unsigned char* src = nf8
                + ((size_t)((pti * 16 + rf) * 4 + pc)) * 2048 + half * 1024 + l * 16;
            __builtin_amdgcn_global_load_lds(
                (const __attribute__((address_space(1))) void*)src,
                (__attribute__((address_space(3))) void*)(dAb + t * 1024), 16, 0, 0);
        }
    };
    // load this wave's 2 B-frags for chunk pc (4 VMEM dwordx4 instrs)
    auto bload = [&](int ptj, int pc, i32x8* dst) {
        #pragma unroll
        for (int ni = 0; ni < 2; ++ni)
            dst[ni] = *(const i32x8*)(nf8
                + ((size_t)((ptj * 8 + wc * 2 + ni) * 4 + pc)) * 2048 + l * 32);
    };

    float acc0 = 0.f, acc1 = 0.f;

    int u = blockIdx.x;
    int ti, tj;
    decode_unit(u, ti, tj);

    i32x8 bfe[2], bfo[2];

    // pipeline prologue: unit-0 chunk-0 (A -> As[0], B -> even regs)
    bload(tj, 0, bfe);
    stageA(As[0], ti, 0);

    while (u < NUNITS) {
        int u_next = u + GRID;
        bool have_next = (u_next < NUNITS);
        int ti_n = 0, tj_n = 0;
        if (have_next) decode_unit(u_next, ti_n, tj_n);

        f32x4 accv[8][2] = {};

        #pragma unroll 1
        for (int cc = 0; cc < 2; ++cc) {
            // ===== even chunk e = 2cc (A in As[0], B in bfe) =====
            bload(tj, 2 * cc + 1, bfo);          // B for odd chunk, 1 ahead
            stageA(As[1], ti, 2 * cc + 1);       // A for odd chunk
            asm volatile("s_waitcnt vmcnt(8)" ::: "memory"); // dma(e)+bfe landed
            asm volatile("s_barrier" ::: "memory");
            __builtin_amdgcn_s_setprio(1);
            #pragma unroll
            for (int mi = 0; mi < 8; ++mi) {
                i32x8 af = *(const i32x8*)(As[0] + (wr * 8 + mi) * 2048 + l * 32);
                #pragma unroll
                for (int ni = 0; ni < 2; ++ni)
                    accv[mi][ni] = __builtin_amdgcn_mfma_scale_f32_16x16x128_f8f6f4(
                        af, bfe[ni], accv[mi][ni],
                        0, 0, 0, 0x7F7F7F7F, 0, 0x7F7F7F7F);
            }
            __builtin_amdgcn_s_setprio(0);
            asm volatile("s_barrier" ::: "memory");   // As[0] readers done

            // ===== odd chunk o = 2cc+1 (A in As[1], B in bfo) =====
            bool more = (cc == 0) || have_next;
            int nti = (cc == 0) ? ti : ti_n;
            int ntj = (cc == 0) ? tj : tj_n;
            int nc  = (cc == 0) ? 2 : 0;
            if (more) {
                bload(ntj, nc, bfe);             // B for next even chunk
                stageA(As[0], nti, nc);          // A for next even chunk
                asm volatile("s_waitcnt vmcnt(8)" ::: "memory"); // dma(o)+bfo landed
            } else {
                asm volatile("s_waitcnt vmcnt(0)" ::: "memory");  // end of work
            }
            asm volatile("s_barrier" ::: "memory");
            __builtin_amdgcn_s_setprio(1);
            #pragma unroll
            for (int mi = 0; mi < 8; ++mi) {
                i32x8 af = *(const i32x8*)(As[1] + (wr * 8 + mi) * 2048 + l * 32);
                #pragma unroll
                for (int ni = 0; ni < 2; ++ni)
                    accv[mi][ni] = __builtin_amdgcn_mfma_scale_f32_16x16x128_f8f6f4(
                        af, bfo[ni], accv[mi][ni],
                        0, 0, 0, 0x7F7F7F7F, 0, 0x7F7F7F7F);
            }
            __builtin_amdgcn_s_setprio(0);
            asm volatile("s_barrier" ::: "memory");   // As[1] readers done
        }

        // ---- per-unit epilogue (C/D layout: col=lane&15 -> j, row=q*4+reg -> i) ----
        // wave covers global rows ti*256 + wr*128 + [0,128), cols tj*128 + wc*32 + [0,32)
        {
            int jb = tj * 128 + wc * 32 + lr;
            float sqj[2]; int yj[2];
            #pragma unroll
            for (int ni = 0; ni < 2; ++ni) {
                sqj[ni] = sq[jb + ni * 16];
                yj[ni]  = y[jb + ni * 16];
            }
            // triangle classification at wave level:
            //   skip:  tj==2ti && wr==1       (cols < rows entirely)
            //   full:  tj>2ti+1, or tj==2ti+1 && wr==0
            //   partial (local test colLocal>=rowLocal, offsets cancel):
            //          tj==2ti && wr==0,  or  tj==2ti+1 && wr==1
            bool skip = (tj == 2 * ti) && (wr == 1);
            bool full = (tj > 2 * ti + 1) || ((tj == 2 * ti + 1) && (wr == 0));
            if (!skip) {
                if (full) {
                    #pragma unroll
                    for (int mi = 0; mi < 8; ++mi) {
                        #pragma unroll
                        for (int r = 0; r < 4; ++r) {
                            int ia = ti * 256 + wr * 128 + mi * 16 + q * 4 + r;
                            float ci = THETA - sq[ia];
                            int yi = y[ia];
                            float h0 = fmaxf(fmaf(2.f, accv[mi][0][r], ci - sqj[0]), 0.f);
                            acc0 += (yi == yj[0]) ? h0 : -h0;
                            float h1 = fmaxf(fmaf(2.f, accv[mi][1][r], ci - sqj[1]), 0.f);
                            acc1 += (yi == yj[1]) ? h1 : -h1;
                        }
                    }
                } else {
                    // straddling: keep when wc*32+ni*16+lr >= mi*16+q*4+r
                    #pragma unroll
                    for (int mi = 0; mi < 8; ++mi) {
                        #pragma unroll
                        for (int r = 0; r < 4; ++r) {
                            int rl_ = mi * 16 + q * 4 + r;             // local row
                            int ia = ti * 256 + wr * 128 + rl_;
                            float ci = THETA - sq[ia];
                            int yi = y[ia];
                            #pragma unroll
                            for (int ni = 0; ni < 2; ++ni) {
                                float h = fmaxf(fmaf(2.f, accv[mi][ni][r], ci - sqj[ni]), 0.f);
                                float sh = (yi == yj[ni]) ? h : -h;
                                if (wc * 32 + ni * 16 + lr >= rl_) acc0 += sh;
                            }
                        }
                    }
                }
            }
        }

        u = u_next; ti = ti_n; tj = tj_n;
    }

    float local = acc0 + acc1;
    #pragma unroll
    for (int off = 32; off > 0; off >>= 1) local += __shfl_down(local, off);
    if (l == 0) wpart[w] = local;
    __syncthreads();
    if (tid == 0) {
        double ssum = 0.0;
        #pragma unroll
        for (int i = 0; i < 8; ++i) ssum += (double)wpart[i];
        __hip_atomic_store(&part[blockIdx.x], ssum, __ATOMIC_RELEASE, __HIP_MEMORY_SCOPE_AGENT);
        unsigned int ticket = __hip_atomic_fetch_add(
            counter, 1u, __ATOMIC_ACQ_REL, __HIP_MEMORY_SCOPE_AGENT);
        is_last = (ticket == GRID - 1) ? 1 : 0;
    }
    __syncthreads();
    if (is_last) {
        double s = 0.0;
        for (int i = tid; i < GRID; i += 512)
            s += __hip_atomic_load(&part[i], __ATOMIC_ACQUIRE, __HIP_MEMORY_SCOPE_AGENT);
        #pragma unroll
        for (int off = 32; off > 0; off >>= 1) s += __shfl_down(s, off);
        if (l == 0) dpart[w] = s;
        __syncthreads();
        if (tid == 0) {
            double t8 = 0.0;
            #pragma unroll
            for (int i = 0; i < 8; ++i) t8 += dpart[i];
            // add the analytically-known XI term: XI * #upper-tri pairs
            double total = t8 + (double)XI * NPAIRS_UP;
            const double m = 1.0 / ((double)BDIM * (double)BDIM - (double)BDIM);
            out[0] = (float)(total * m);
        }
    }
}

extern "C" void kernel_launch(void* const* d_in, const int* in_sizes, int n_in,
                              void* d_out, int out_size, void* d_ws, size_t ws_size,
                              hipStream_t stream) {
    const float* x = (const float*)d_in[0];
    const int* y = (const int*)d_in[1];
    float* out = (float*)d_out;

    unsigned char* nf8 = (unsigned char*)d_ws;                          // 4 MB fp8 (tiled)
    char* p = (char*)d_ws + (size_t)BDIM * DDIM;
    float* sq = (float*)p;                                              // 32 KB
    unsigned int* counter = (unsigned int*)(p + (size_t)BDIM * 4);
    double* part = (double*)(p + (size_t)BDIM * 4 + 64);                // GRID doubles

    normalize_rows<<<BDIM / 4, 256, 0, stream>>>(x, nf8, sq, counter);
    gram_hinge<<<GRID, 512, 0, stream>>>(nf8, sq, y, part, counter, out);
}